// Round 3
// baseline (935.368 us; speedup 1.0000x reference)
//
#include <hip/hip_runtime.h>

typedef __bf16 bf16x8 __attribute__((ext_vector_type(8)));
typedef float f32x16 __attribute__((ext_vector_type(16)));

#define K_DIM 256

// ---------------------------------------------------------------------------
// Prep 1: weight-norm a (rows x 256) fp32 matrix. Optionally write:
//   dstb: bf16, k-chunk-major layout per 256-row chunk-block:
//         [r>>8][k>>3][r&255][8]
//   dstf: fp32, row-major (cond path)
// One wave per row.
// ---------------------------------------------------------------------------
__global__ void wn_kernel(const float* __restrict__ v, const float* __restrict__ gv,
                          __bf16* __restrict__ dstb, float* __restrict__ dstf) {
  const int r = blockIdx.x;
  const int l = threadIdx.x;  // 64 threads
  const float* vr = v + (size_t)r * K_DIM;
  float4 p = *reinterpret_cast<const float4*>(vr + l * 4);
  float ss = p.x * p.x + p.y * p.y + p.z * p.z + p.w * p.w;
#pragma unroll
  for (int m = 1; m <= 32; m <<= 1) ss += __shfl_xor(ss, m, 64);
  const float sc = gv[r] * rsqrtf(ss);
  const float a0 = p.x * sc, a1 = p.y * sc, a2 = p.z * sc, a3 = p.w * sc;
  if (dstf != nullptr) {
    float4 o; o.x = a0; o.y = a1; o.z = a2; o.w = a3;
    *reinterpret_cast<float4*>(dstf + (size_t)r * K_DIM + l * 4) = o;
  }
  if (dstb != nullptr) {
    __bf16* d = dstb + ((size_t)(r >> 8) << 16) +
                ((size_t)((l >> 1) << 8) + (r & 255)) * 8 + (l & 1) * 4;
    d[0] = (__bf16)a0; d[1] = (__bf16)a1; d[2] = (__bf16)a2; d[3] = (__bf16)a3;
  }
}

// ---------------------------------------------------------------------------
// Prep 2: gbuf[g][0:256]  = gamma = cond @ wnc^T + b_cond + 1
//         gbuf[g][256:512]= beta  = cond @ wnc^T + b_cond
// ---------------------------------------------------------------------------
__global__ void gb_kernel(const float* __restrict__ cond, const float* __restrict__ wncf,
                          const float* __restrict__ bc, float* __restrict__ gbuf) {
  const int gidx = blockIdx.x;
  const int t = threadIdx.x;  // 256
  __shared__ float c[256];
  c[t] = cond[(size_t)gidx * 256 + t];
  __syncthreads();
#pragma unroll
  for (int h = 0; h < 2; ++h) {
    const int o = (h << 8) + t;
    const float* wr = wncf + (size_t)o * 256;
    float s = 0.0f;
#pragma unroll 8
    for (int k = 0; k < 256; k += 4) {
      const float4 w4 = *reinterpret_cast<const float4*>(wr + k);
      s += c[k] * w4.x + c[k + 1] * w4.y + c[k + 2] * w4.z + c[k + 3] * w4.w;
    }
    gbuf[(size_t)gidx * 512 + o] = s + bc[o] + (h == 0 ? 1.0f : 0.0f);
  }
}

// ---------------------------------------------------------------------------
// Main fused kernel v4: v1 geometry + counted-vmcnt ring pipeline (T3+T4).
//   64 rows/block, 128 threads = 2 waves, wave = 32 rows x 256 cols,
//   16 MFMA per wave per K-tile, wave-local LN (no cross-wave exchange).
// Weight stream: 32 tiles of 16 KiB (W1 x8, W2 x8, W3 x16) through a 3-slot
// LDS ring. Per iteration:
//   s_waitcnt vmcnt(8)   <- tile kt landed; tile kt+1 STAYS IN FLIGHT
//   s_barrier (raw asm)  <- no implicit vmcnt(0) drain (v3's fatal flaw)
//   stage(kt+2)          <- into the slot all waves finished last iteration
//   compute(kt)          <- 16 MFMA + 18 ds_read_b128
// vmcnt(8) is always <= the true count of ops younger than tile kt (stores/
// gbuf loads issued later only make it more conservative), so it is safe
// everywhere; only the final tile needs vmcnt(0).
// LDS: Abuf 32 KiB (XOR-swizzled, 0 bank conflicts per v3) + ring 48 KiB
//   = 80 KiB -> 2 blocks/CU (4 waves/CU, co-resident block covers stalls).
// All prologue VMEM (x row, bids, b2, b3) is issued before tile 0 and pinned
// with empty asm so the compiler cannot sink the loads back into the loop.
// ---------------------------------------------------------------------------
__global__ __launch_bounds__(128, 1) void fused_kernel(
    const float* __restrict__ x, const int* __restrict__ bids,
    const __bf16* __restrict__ W1t, const __bf16* __restrict__ W2t,
    const __bf16* __restrict__ W3t, const float* __restrict__ gbuf,
    const float* __restrict__ b2, const float* __restrict__ b3,
    float* __restrict__ out, const int n) {
  __shared__ __bf16 Abuf[32 * 64 * 8];   // 32 KiB, [kc][slot^swz][8]
  __shared__ __bf16 Wring[3][8192];      // 3 x 16 KiB ring

  const int t = threadIdx.x;
  const int lane = t & 63;
  const int w = t >> 6;        // 0..1
  const int nlo = lane & 31;
  const int g = lane >> 5;
  const int mbase = w << 5;    // this wave's row base (0/32)
  const int R = blockIdx.x << 6;

  // Abuf swizzled element index (v3-verified: SQ_LDS_BANK_CONFLICT = 0)
  auto aidx = [](int kc, int row) { return ((kc << 6) + (row ^ (kc & 7))) << 3; };

  // stream tile t (16 KiB) source pointer
  auto src_of = [&](int tt) -> const __bf16* {
    const __bf16* p = W1t + ((size_t)tt << 13);
    if (tt >= 8)  p = W2t + ((size_t)(tt - 8) << 13);
    if (tt >= 16) p = W3t + ((size_t)(tt - 16) << 13);
    return p;
  };

  // stage one 16 KiB tile into dst: 16 x 1 KiB wave-chunks, 8 per wave
  // -> 8 global_load_lds (16 B/lane) per thread per tile.
  auto stage = [&](__bf16* dst, const __bf16* src) {
#pragma unroll
    for (int i = 0; i < 8; ++i) {
      const int c = (w << 3) + i;
      __builtin_amdgcn_global_load_lds(
          (const __attribute__((address_space(1))) void*)(src + (c << 9) + (lane << 3)),
          (__attribute__((address_space(3))) void*)(dst + (c << 9)), 16, 0, 0);
    }
  };

  f32x16 acc[8];
  auto zero_acc = [&]() {
#pragma unroll
    for (int nt = 0; nt < 8; ++nt)
#pragma unroll
      for (int e = 0; e < 16; ++e) acc[nt][e] = 0.0f;
  };

  // ---------------- prologue: all dirty VMEM before tile 0 ----------------
  int row = R + mbase + nlo;
  if (row >= n) row = n - 1;
  const float* xrow = x + (size_t)row * K_DIM;
  float4 xp[32];
#pragma unroll
  for (int i = 0; i < 16; ++i) {
    const int kc = (i << 1) + g;
    xp[2 * i]     = *reinterpret_cast<const float4*>(xrow + (kc << 3));
    xp[2 * i + 1] = *reinterpret_cast<const float4*>(xrow + (kc << 3) + 4);
  }
  int bidv[16];
#pragma unroll
  for (int reg = 0; reg < 16; ++reg) {
    const int rl = (reg & 3) + ((reg >> 2) << 3) + (g << 2);
    int rg = R + mbase + rl;
    if (rg >= n) rg = n - 1;
    bidv[reg] = bids[rg];
  }
  float b2v[8], b3v0[8], b3v1[8];
#pragma unroll
  for (int nt = 0; nt < 8; ++nt) {
    const int col = (nt << 5) + nlo;
    b2v[nt]  = b2[col];
    b3v0[nt] = b3[col];
    b3v1[nt] = b3[256 + col];
  }
  // pin: force issue here and keep resident (stop rematerialization/sinking)
#pragma unroll
  for (int i = 0; i < 32; ++i)
    asm volatile("" :: "v"(xp[i].x), "v"(xp[i].y), "v"(xp[i].z), "v"(xp[i].w));
#pragma unroll
  for (int reg = 0; reg < 16; ++reg) asm volatile("" :: "v"(bidv[reg]));
#pragma unroll
  for (int nt = 0; nt < 8; ++nt)
    asm volatile("" :: "v"(b2v[nt]), "v"(b3v0[nt]), "v"(b3v1[nt]));

  stage(&Wring[0][0], src_of(0));
  stage(&Wring[1][0], src_of(1));
  __bf16* wa = &Wring[0][0];
  __bf16* wb = &Wring[1][0];
  __bf16* wc = &Wring[2][0];

#define PIPE_HEAD(TCUR)                                          \
  asm volatile("s_waitcnt vmcnt(8)" ::: "memory");               \
  asm volatile("s_barrier" ::: "memory");                        \
  if ((TCUR) + 2 < 32) stage(wc, src_of((TCUR) + 2));

#define ROTATE() { __bf16* _tmp = wa; wa = wb; wb = wc; wc = _tmp; }

  // ---------------- segment 1: s1 = x @ W1^T (tiles 0..7) ----------------
  zero_acc();
#pragma unroll
  for (int kt = 0; kt < 8; ++kt) {
    PIPE_HEAD(kt)
#pragma unroll
    for (int ks = 0; ks < 2; ++ks) {
      const int i = kt * 2 + ks;
      const float4 p = xp[2 * i], q = xp[2 * i + 1];
      bf16x8 a;
      a[0] = (__bf16)p.x; a[1] = (__bf16)p.y; a[2] = (__bf16)p.z; a[3] = (__bf16)p.w;
      a[4] = (__bf16)q.x; a[5] = (__bf16)q.y; a[6] = (__bf16)q.z; a[7] = (__bf16)q.w;
#pragma unroll
      for (int nt = 0; nt < 8; ++nt) {
        const bf16x8 b = *reinterpret_cast<const bf16x8*>(
            &wa[((((ks << 1) + g) << 8) + (nt << 5) + nlo) << 3]);
        acc[nt] = __builtin_amdgcn_mfma_f32_32x32x16_bf16(a, b, acc[nt], 0, 0, 0);
      }
    }
    ROTATE()
  }

  // ---------------- layernorm + FiLM + relu -> Abuf (wave-local) ----------
  // Tiles 8,9 remain in flight; gbuf loads below get compiler-inserted waits
  // (bounded drain, covered by the co-resident block).
  {
    float mu[16], rs[16];
#pragma unroll
    for (int reg = 0; reg < 16; ++reg) {
      float s = 0.0f, q = 0.0f;
#pragma unroll
      for (int nt = 0; nt < 8; ++nt) {
        const float v = acc[nt][reg];
        s += v; q += v * v;
      }
#pragma unroll
      for (int m = 1; m <= 16; m <<= 1) {  // reduce over the 32-lane half-wave
        s += __shfl_xor(s, m, 64);
        q += __shfl_xor(q, m, 64);
      }
      const float mean = s * (1.0f / 256.0f);
      const float var = q * (1.0f / 256.0f) - mean * mean;
      mu[reg] = mean;
      rs[reg] = rsqrtf(var + 1e-5f);
    }
#pragma unroll
    for (int reg = 0; reg < 16; ++reg) {
      const int rl = (reg & 3) + ((reg >> 2) << 3) + (g << 2);
      const int rowi = mbase + rl;
      const float* grow = gbuf + ((size_t)bidv[reg] << 9);
#pragma unroll
      for (int nt = 0; nt < 8; ++nt) {
        const int col = (nt << 5) + nlo;
        float v = (acc[nt][reg] - mu[reg]) * rs[reg];
        v = v * grow[col] + grow[256 + col];
        v = v > 0.0f ? v : 0.0f;
        Abuf[aidx(col >> 3, rowi) + (col & 7)] = (__bf16)v;
      }
    }
  }

  // ---------------- segment 2: relu(h @ W2^T + b2) (tiles 8..15) ---------
  zero_acc();
#pragma unroll
  for (int kt = 0; kt < 8; ++kt) {
    PIPE_HEAD(8 + kt)
#pragma unroll
    for (int ks = 0; ks < 2; ++ks) {
      const int kcf = kt * 4 + ks * 2 + g;
      const bf16x8 a = *reinterpret_cast<const bf16x8*>(&Abuf[aidx(kcf, mbase + nlo)]);
#pragma unroll
      for (int nt = 0; nt < 8; ++nt) {
        const bf16x8 b = *reinterpret_cast<const bf16x8*>(
            &wa[((((ks << 1) + g) << 8) + (nt << 5) + nlo) << 3]);
        acc[nt] = __builtin_amdgcn_mfma_f32_32x32x16_bf16(a, b, acc[nt], 0, 0, 0);
      }
    }
    ROTATE()
  }
  {  // epilogue: relu + b2 -> Abuf (own rows only; no barrier needed)
#pragma unroll
    for (int reg = 0; reg < 16; ++reg) {
      const int rl = (reg & 3) + ((reg >> 2) << 3) + (g << 2);
      const int rowi = mbase + rl;
#pragma unroll
      for (int nt = 0; nt < 8; ++nt) {
        const int col = (nt << 5) + nlo;
        float v = acc[nt][reg] + b2v[nt];
        v = v > 0.0f ? v : 0.0f;
        Abuf[aidx(col >> 3, rowi) + (col & 7)] = (__bf16)v;
      }
    }
  }

  // ---------------- segment 3: out half 0 (tiles 16..23) ------------------
  zero_acc();
#pragma unroll
  for (int kt = 0; kt < 8; ++kt) {
    PIPE_HEAD(16 + kt)
#pragma unroll
    for (int ks = 0; ks < 2; ++ks) {
      const int kcf = kt * 4 + ks * 2 + g;
      const bf16x8 a = *reinterpret_cast<const bf16x8*>(&Abuf[aidx(kcf, mbase + nlo)]);
#pragma unroll
      for (int nt = 0; nt < 8; ++nt) {
        const bf16x8 b = *reinterpret_cast<const bf16x8*>(
            &wa[((((ks << 1) + g) << 8) + (nt << 5) + nlo) << 3]);
        acc[nt] = __builtin_amdgcn_mfma_f32_32x32x16_bf16(a, b, acc[nt], 0, 0, 0);
      }
    }
    ROTATE()
  }
  {  // epilogue: store half 0 (stores are younger than in-flight tiles ->
     // later vmcnt(8) waits stay conservative-safe)
#pragma unroll
    for (int reg = 0; reg < 16; ++reg) {
      const int rl = (reg & 3) + ((reg >> 2) << 3) + (g << 2);
      const int rglob = R + mbase + rl;
      if (rglob < n) {
        float* orow = out + (size_t)rglob * 512;
#pragma unroll
        for (int nt = 0; nt < 8; ++nt) orow[(nt << 5) + nlo] = acc[nt][reg] + b3v0[nt];
      }
    }
  }

  // ---------------- segment 4: out half 1 (tiles 24..31) ------------------
  zero_acc();
#pragma unroll
  for (int kt = 0; kt < 8; ++kt) {
    if (kt == 7) {
      asm volatile("s_waitcnt vmcnt(0)" ::: "memory");  // final tile: full drain
    } else {
      asm volatile("s_waitcnt vmcnt(8)" ::: "memory");
    }
    asm volatile("s_barrier" ::: "memory");
    if (24 + kt + 2 < 32) stage(wc, src_of(24 + kt + 2));
#pragma unroll
    for (int ks = 0; ks < 2; ++ks) {
      const int kcf = kt * 4 + ks * 2 + g;
      const bf16x8 a = *reinterpret_cast<const bf16x8*>(&Abuf[aidx(kcf, mbase + nlo)]);
#pragma unroll
      for (int nt = 0; nt < 8; ++nt) {
        const bf16x8 b = *reinterpret_cast<const bf16x8*>(
            &wa[((((ks << 1) + g) << 8) + (nt << 5) + nlo) << 3]);
        acc[nt] = __builtin_amdgcn_mfma_f32_32x32x16_bf16(a, b, acc[nt], 0, 0, 0);
      }
    }
    ROTATE()
  }
  {  // epilogue: store half 1
#pragma unroll
    for (int reg = 0; reg < 16; ++reg) {
      const int rl = (reg & 3) + ((reg >> 2) << 3) + (g << 2);
      const int rglob = R + mbase + rl;
      if (rglob < n) {
        float* orow = out + (size_t)rglob * 512 + 256;
#pragma unroll
        for (int nt = 0; nt < 8; ++nt) orow[(nt << 5) + nlo] = acc[nt][reg] + b3v1[nt];
      }
    }
  }
#undef PIPE_HEAD
#undef ROTATE
}

extern "C" void kernel_launch(void* const* d_in, const int* in_sizes, int n_in,
                              void* d_out, int out_size, void* d_ws, size_t ws_size,
                              hipStream_t stream) {
  const float* x      = (const float*)d_in[0];
  const float* cond   = (const float*)d_in[1];
  const int*   bids   = (const int*)d_in[2];
  const float* v_cond = (const float*)d_in[3];
  const float* g_cond = (const float*)d_in[4];
  const float* b_cond = (const float*)d_in[5];
  const float* v1     = (const float*)d_in[6];
  const float* g1     = (const float*)d_in[7];
  const float* v2     = (const float*)d_in[8];
  const float* g2     = (const float*)d_in[9];
  const float* b2     = (const float*)d_in[10];
  const float* v3     = (const float*)d_in[11];
  const float* g3     = (const float*)d_in[12];
  const float* b3     = (const float*)d_in[13];
  float* out = (float*)d_out;
  const int n = in_sizes[0] / K_DIM;

  // workspace layout
  char* ws = (char*)d_ws;
  __bf16* W1t = (__bf16*)ws;               // 256x256 bf16, k-chunk-major (128 KB)
  __bf16* W2t = W1t + 65536;               // 128 KB
  __bf16* W3t = W2t + 65536;               // 512x256 bf16: [half][kc][256][8] (256 KB)
  float* wncf = (float*)(W3t + 131072);    // 512x256 fp32 normalized v_cond (512 KB)
  float* gbuf = wncf + 131072;             // 256x512 fp32 gamma|beta (512 KB)

  wn_kernel<<<256, 64, 0, stream>>>(v1, g1, W1t, nullptr);
  wn_kernel<<<256, 64, 0, stream>>>(v2, g2, W2t, nullptr);
  wn_kernel<<<512, 64, 0, stream>>>(v3, g3, W3t, nullptr);
  wn_kernel<<<512, 64, 0, stream>>>(v_cond, g_cond, nullptr, wncf);
  gb_kernel<<<256, 256, 0, stream>>>(cond, wncf, b_cond, gbuf);

  const int nb = (n + 63) / 64;
  fused_kernel<<<nb, 128, 0, stream>>>(x, bids, W1t, W2t, W3t, gbuf, b2, b3, out, n);
}

// Round 4
// 726.182 us; speedup vs baseline: 1.2881x; 1.2881x over previous
//
#include <hip/hip_runtime.h>

typedef __bf16 bf16x8 __attribute__((ext_vector_type(8)));
typedef float f32x16 __attribute__((ext_vector_type(16)));

#define K_DIM 256

// ---------------------------------------------------------------------------
// Prep 1: weight-norm a (rows x 256) fp32 matrix. Optionally write:
//   dstb: bf16, k-chunk-major layout per 256-row chunk-block:
//         [r>>8][k>>3][r&255][8]
//   dstf: fp32, row-major (cond path)
// One wave per row.
// ---------------------------------------------------------------------------
__global__ void wn_kernel(const float* __restrict__ v, const float* __restrict__ gv,
                          __bf16* __restrict__ dstb, float* __restrict__ dstf) {
  const int r = blockIdx.x;
  const int l = threadIdx.x;  // 64 threads
  const float* vr = v + (size_t)r * K_DIM;
  float4 p = *reinterpret_cast<const float4*>(vr + l * 4);
  float ss = p.x * p.x + p.y * p.y + p.z * p.z + p.w * p.w;
#pragma unroll
  for (int m = 1; m <= 32; m <<= 1) ss += __shfl_xor(ss, m, 64);
  const float sc = gv[r] * rsqrtf(ss);
  const float a0 = p.x * sc, a1 = p.y * sc, a2 = p.z * sc, a3 = p.w * sc;
  if (dstf != nullptr) {
    float4 o; o.x = a0; o.y = a1; o.z = a2; o.w = a3;
    *reinterpret_cast<float4*>(dstf + (size_t)r * K_DIM + l * 4) = o;
  }
  if (dstb != nullptr) {
    __bf16* d = dstb + ((size_t)(r >> 8) << 16) +
                ((size_t)((l >> 1) << 8) + (r & 255)) * 8 + (l & 1) * 4;
    d[0] = (__bf16)a0; d[1] = (__bf16)a1; d[2] = (__bf16)a2; d[3] = (__bf16)a3;
  }
}

// ---------------------------------------------------------------------------
// Prep 2: gbuf[g][0:256]  = gamma = cond @ wnc^T + b_cond + 1
//         gbuf[g][256:512]= beta  = cond @ wnc^T + b_cond
// ---------------------------------------------------------------------------
__global__ void gb_kernel(const float* __restrict__ cond, const float* __restrict__ wncf,
                          const float* __restrict__ bc, float* __restrict__ gbuf) {
  const int gidx = blockIdx.x;
  const int t = threadIdx.x;  // 256
  __shared__ float c[256];
  c[t] = cond[(size_t)gidx * 256 + t];
  __syncthreads();
#pragma unroll
  for (int h = 0; h < 2; ++h) {
    const int o = (h << 8) + t;
    const float* wr = wncf + (size_t)o * 256;
    float s = 0.0f;
#pragma unroll 8
    for (int k = 0; k < 256; k += 4) {
      const float4 w4 = *reinterpret_cast<const float4*>(wr + k);
      s += c[k] * w4.x + c[k + 1] * w4.y + c[k + 2] * w4.z + c[k + 3] * w4.w;
    }
    gbuf[(size_t)gidx * 512 + o] = s + bc[o] + (h == 0 ? 1.0f : 0.0f);
  }
}

// ---------------------------------------------------------------------------
// Main fused kernel v5: v1's proven structure, widened to 128 rows/block.
//   256 threads = 4 waves, each wave owns 32 rows x 256 cols (16 MFMA/tile,
//   identical per-wave code to v1). LN stays wave-local.
// Per weight K-tile (16 KiB): sync; stage (global_load_lds); sync; compute.
//   (v1's discipline — the only sync structure that has worked. The 32
//   tile-stages per block now serve 128 rows instead of 64 -> per-row drain
//   cost halves.)
// LDS: Abuf 64 KiB (XOR-swizzled: row ^ (kc&7), v3-verified 0 conflicts)
//    + Wbuf 16 KiB = 80 KiB -> 2 blocks/CU -> 8 waves/CU cover.
// ---------------------------------------------------------------------------
__global__ __launch_bounds__(256, 2) void fused_kernel(
    const float* __restrict__ x, const int* __restrict__ bids,
    const __bf16* __restrict__ W1t, const __bf16* __restrict__ W2t,
    const __bf16* __restrict__ W3t, const float* __restrict__ gbuf,
    const float* __restrict__ b2, const float* __restrict__ b3,
    float* __restrict__ out, const int n) {
  __shared__ __bf16 Abuf[32 * 128 * 8];  // 64 KiB: h tile, [kc][row^swz][8]
  __shared__ __bf16 Wbuf[4 * 256 * 8];   // 16 KiB: weight K-tile, [kc][out][8]

  const int t = threadIdx.x;
  const int lane = t & 63;
  const int w = t >> 6;        // 0..3
  const int nlo = lane & 31;   // MFMA m / n lane index
  const int g = lane >> 5;     // MFMA k-group
  const int mbase = w << 5;    // this wave's row base within the 128-row tile
  const int R = blockIdx.x << 7;

  // Abuf swizzled element index (plane stride 128 rows x 16 B = 2 KiB,
  // bank-aligned; XOR spreads the 4 planes a store touches across bank quads)
  auto aidx = [](int kc, int row) { return ((kc << 7) + (row ^ (kc & 7))) << 3; };

  f32x16 zero;
#pragma unroll
  for (int e = 0; e < 16; ++e) zero[e] = 0.0f;

  f32x16 acc[8];

  // stage a 16 KiB weight K-tile [kc 0..3][out 0..255][8] into Wbuf.
  // 1024 x 16 B chunks over 256 threads -> 4 global_load_lds per thread.
  auto stage_w = [&](const __bf16* wsrc, int kt, int outr, int outbase) {
#pragma unroll
    for (int it = 0; it < 4; ++it) {
      const int cid = (((w << 2) + it) << 6) + lane;  // 16B-chunk id 0..1023
      const int kc = cid >> 8;
      const int outl = cid & 255;
      const __bf16* gp = wsrc + ((size_t)((kt * 4 + kc) * outr + outbase + outl) << 3);
      __builtin_amdgcn_global_load_lds(
          (const __attribute__((address_space(1))) void*)gp,
          (__attribute__((address_space(3))) void*)(&Wbuf[(((w << 2) + it)) << 9]),
          16, 0, 0);
    }
  };

  // ---------------- stage 1: s1 = x @ W1^T ----------------
#pragma unroll
  for (int nt = 0; nt < 8; ++nt) acc[nt] = zero;
  {
    int row = R + mbase + nlo;
    if (row >= n) row = n - 1;
    const float* xrow = x + (size_t)row * K_DIM;
    for (int kt = 0; kt < 8; ++kt) {
      __syncthreads();
      stage_w(W1t, kt, 256, 0);
      // x fragments for this kt (issued while the stage is in flight)
      const int k0 = kt * 32 + g * 8;
      const float4 p0 = *reinterpret_cast<const float4*>(xrow + k0);
      const float4 q0 = *reinterpret_cast<const float4*>(xrow + k0 + 4);
      const float4 p1 = *reinterpret_cast<const float4*>(xrow + k0 + 16);
      const float4 q1 = *reinterpret_cast<const float4*>(xrow + k0 + 20);
      bf16x8 a[2];
      a[0][0] = (__bf16)p0.x; a[0][1] = (__bf16)p0.y; a[0][2] = (__bf16)p0.z; a[0][3] = (__bf16)p0.w;
      a[0][4] = (__bf16)q0.x; a[0][5] = (__bf16)q0.y; a[0][6] = (__bf16)q0.z; a[0][7] = (__bf16)q0.w;
      a[1][0] = (__bf16)p1.x; a[1][1] = (__bf16)p1.y; a[1][2] = (__bf16)p1.z; a[1][3] = (__bf16)p1.w;
      a[1][4] = (__bf16)q1.x; a[1][5] = (__bf16)q1.y; a[1][6] = (__bf16)q1.z; a[1][7] = (__bf16)q1.w;
      __syncthreads();
#pragma unroll
      for (int ks = 0; ks < 2; ++ks) {
#pragma unroll
        for (int nt = 0; nt < 8; ++nt) {
          const bf16x8 b = *reinterpret_cast<const bf16x8*>(
              &Wbuf[((((ks << 1) + g) << 8) + (nt << 5) + nlo) << 3]);
          acc[nt] = __builtin_amdgcn_mfma_f32_32x32x16_bf16(a[ks], b, acc[nt], 0, 0, 0);
        }
      }
    }
  }

  // ---------------- layernorm + FiLM + relu -> Abuf (wave-local) ----------
  {
    float mu[16], rs[16];
#pragma unroll
    for (int reg = 0; reg < 16; ++reg) {
      float s = 0.0f, q = 0.0f;
#pragma unroll
      for (int nt = 0; nt < 8; ++nt) {
        const float v = acc[nt][reg];
        s += v; q += v * v;
      }
#pragma unroll
      for (int m = 1; m <= 16; m <<= 1) {  // reduce over the 32-lane half-wave
        s += __shfl_xor(s, m, 64);
        q += __shfl_xor(q, m, 64);
      }
      const float mean = s * (1.0f / 256.0f);
      const float var = q * (1.0f / 256.0f) - mean * mean;
      mu[reg] = mean;
      rs[reg] = rsqrtf(var + 1e-5f);
    }
#pragma unroll
    for (int reg = 0; reg < 16; ++reg) {
      const int rl = (reg & 3) + ((reg >> 2) << 3) + (g << 2);  // C-layout row 0..31
      int rglob = R + mbase + rl;
      if (rglob >= n) rglob = n - 1;
      const int bid = bids[rglob];
      const float* grow = gbuf + ((size_t)bid << 9);
      const int rowi = mbase + rl;
#pragma unroll
      for (int nt = 0; nt < 8; ++nt) {
        const int col = (nt << 5) + nlo;
        float v = (acc[nt][reg] - mu[reg]) * rs[reg];
        v = v * grow[col] + grow[256 + col];
        v = v > 0.0f ? v : 0.0f;
        Abuf[aidx(col >> 3, rowi) + (col & 7)] = (__bf16)v;
      }
    }
  }

  // ---------------- stage 2: relu(h @ W2^T + b2) -> Abuf ----------------
#pragma unroll
  for (int nt = 0; nt < 8; ++nt) acc[nt] = zero;
  for (int kt = 0; kt < 8; ++kt) {
    __syncthreads();
    stage_w(W2t, kt, 256, 0);
    __syncthreads();
#pragma unroll
    for (int ks = 0; ks < 2; ++ks) {
      const int kcf = kt * 4 + ks * 2 + g;
      const bf16x8 a = *reinterpret_cast<const bf16x8*>(&Abuf[aidx(kcf, mbase + nlo)]);
#pragma unroll
      for (int nt = 0; nt < 8; ++nt) {
        const bf16x8 b = *reinterpret_cast<const bf16x8*>(
            &Wbuf[((((ks << 1) + g) << 8) + (nt << 5) + nlo) << 3]);
        acc[nt] = __builtin_amdgcn_mfma_f32_32x32x16_bf16(a, b, acc[nt], 0, 0, 0);
      }
    }
  }
  {
    float b2v[8];
#pragma unroll
    for (int nt = 0; nt < 8; ++nt) b2v[nt] = b2[(nt << 5) + nlo];
#pragma unroll
    for (int reg = 0; reg < 16; ++reg) {
      const int rl = (reg & 3) + ((reg >> 2) << 3) + (g << 2);
      const int rowi = mbase + rl;
#pragma unroll
      for (int nt = 0; nt < 8; ++nt) {
        const int col = (nt << 5) + nlo;
        float v = acc[nt][reg] + b2v[nt];
        v = v > 0.0f ? v : 0.0f;
        Abuf[aidx(col >> 3, rowi) + (col & 7)] = (__bf16)v;
      }
    }
  }

  // ---------------- stage 3: out = h2 @ W3^T + b3 (two 256-col halves) ----
  // W3t layout: [half][kc][256][8] (two 64-KiB half-blocks).
  for (int half = 0; half < 2; ++half) {
#pragma unroll
    for (int nt = 0; nt < 8; ++nt) acc[nt] = zero;
    const __bf16* w3h = W3t + ((size_t)half << 16);
    for (int kt = 0; kt < 8; ++kt) {
      __syncthreads();
      stage_w(w3h, kt, 256, 0);
      __syncthreads();
#pragma unroll
      for (int ks = 0; ks < 2; ++ks) {
        const int kcf = kt * 4 + ks * 2 + g;
        const bf16x8 a = *reinterpret_cast<const bf16x8*>(&Abuf[aidx(kcf, mbase + nlo)]);
#pragma unroll
        for (int nt = 0; nt < 8; ++nt) {
          const bf16x8 b = *reinterpret_cast<const bf16x8*>(
              &Wbuf[((((ks << 1) + g) << 8) + (nt << 5) + nlo) << 3]);
          acc[nt] = __builtin_amdgcn_mfma_f32_32x32x16_bf16(a, b, acc[nt], 0, 0, 0);
        }
      }
    }
    float b3v[8];
#pragma unroll
    for (int nt = 0; nt < 8; ++nt) b3v[nt] = b3[(half << 8) + (nt << 5) + nlo];
#pragma unroll
    for (int reg = 0; reg < 16; ++reg) {
      const int rl = (reg & 3) + ((reg >> 2) << 3) + (g << 2);
      const int rglob = R + mbase + rl;
      if (rglob < n) {
        float* orow = out + (size_t)rglob * 512 + (half << 8);
#pragma unroll
        for (int nt = 0; nt < 8; ++nt) orow[(nt << 5) + nlo] = acc[nt][reg] + b3v[nt];
      }
    }
  }
}

extern "C" void kernel_launch(void* const* d_in, const int* in_sizes, int n_in,
                              void* d_out, int out_size, void* d_ws, size_t ws_size,
                              hipStream_t stream) {
  const float* x      = (const float*)d_in[0];
  const float* cond   = (const float*)d_in[1];
  const int*   bids   = (const int*)d_in[2];
  const float* v_cond = (const float*)d_in[3];
  const float* g_cond = (const float*)d_in[4];
  const float* b_cond = (const float*)d_in[5];
  const float* v1     = (const float*)d_in[6];
  const float* g1     = (const float*)d_in[7];
  const float* v2     = (const float*)d_in[8];
  const float* g2     = (const float*)d_in[9];
  const float* b2     = (const float*)d_in[10];
  const float* v3     = (const float*)d_in[11];
  const float* g3     = (const float*)d_in[12];
  const float* b3     = (const float*)d_in[13];
  float* out = (float*)d_out;
  const int n = in_sizes[0] / K_DIM;

  // workspace layout
  char* ws = (char*)d_ws;
  __bf16* W1t = (__bf16*)ws;               // 256x256 bf16, k-chunk-major (128 KB)
  __bf16* W2t = W1t + 65536;               // 128 KB
  __bf16* W3t = W2t + 65536;               // 512x256 bf16: [half][kc][256][8] (256 KB)
  float* wncf = (float*)(W3t + 131072);    // 512x256 fp32 normalized v_cond (512 KB)
  float* gbuf = wncf + 131072;             // 256x512 fp32 gamma|beta (512 KB)

  wn_kernel<<<256, 64, 0, stream>>>(v1, g1, W1t, nullptr);
  wn_kernel<<<256, 64, 0, stream>>>(v2, g2, W2t, nullptr);
  wn_kernel<<<512, 64, 0, stream>>>(v3, g3, W3t, nullptr);
  wn_kernel<<<512, 64, 0, stream>>>(v_cond, g_cond, nullptr, wncf);
  gb_kernel<<<256, 256, 0, stream>>>(cond, wncf, b_cond, gbuf);

  const int nb = (n + 127) / 128;
  fused_kernel<<<nb, 256, 0, stream>>>(x, bids, W1t, W2t, W3t, gbuf, b2, b3, out, n);
}